// Round 13
// baseline (318.034 us; speedup 1.0000x reference)
//
#include <hip/hip_runtime.h>

typedef unsigned short u16;
typedef unsigned int u32;
typedef unsigned long long u64;

typedef __attribute__((ext_vector_type(8))) short short8;   // 8 bf16 = 4 VGPRs
typedef __attribute__((ext_vector_type(4))) float floatx4;  // MFMA accumulator

__device__ __forceinline__ float b2f(u16 h) {
  u32 u = ((u32)h) << 16;
  return __builtin_bit_cast(float, u);
}
__device__ __forceinline__ u16 f2b(float f) {
  u32 u = __builtin_bit_cast(u32, f);
  u32 r = 0x7FFFu + ((u >> 16) & 1u);  // RNE
  return (u16)((u + r) >> 16);
}

// async global->LDS, 16B per lane. LDS dest = wave-uniform base + lane*16.
__device__ __forceinline__ void gl_lds16(const void* g, void* l) {
  __builtin_amdgcn_global_load_lds(
      (__attribute__((address_space(1))) void*)(u64)g,
      (__attribute__((address_space(3))) void*)(u32)(u64)l, 16, 0, 0);
}

enum { EPI_PHI_BIAS = 0, EPI_BIAS = 1, EPI_NONE = 2,
       EPI_ZBIAS_F32 = 3 };

// ==================== 256x256 kernel (ALL GEMMs) =============================
// 256x256 tile, 8 waves (2M x 4N, each 128x64, acc[8][4]). BK=64 K-tiles,
// 128B-contiguous staging rows, 2 x 64KB LDS buffers, 4 MFMA quadrants/tile.
// R13: ONE-PHASE-AHEAD register prefetch + compiler-managed counted lgkmcnt.
// R11/R12 exposed full LDS latency every phase (manual lgkmcnt(0) +
// sched_barrier(0) between barrier and MFMA -> ~400cy x 4/tile = the gap to
// the m201 reference). Now each quadrant's fragments are issued >=1 phase
// before their MFMA cluster; no manual lgkmcnt / sched_barrier -> hipcc emits
// minimal counted lgkmcnt (m97 behavior), so MFMA starts with operands ready.
//   P1(u): issue b23(u) reads; stage A-n1,n3(u+1)->bufn; MFMA Q1(aLxb01); BAR
//   P2(u): issue aH(u) reads;  stage A-n0,n2(u+2)->bufc; MFMA Q2(aLxb23); BAR
//   P3(u):                     stage B-n0,n1(u+2)->bufc; MFMA Q3(aHxb23)
//   P4(u): MFMA Q4(aHxb01); vmcnt(4) [memory fence]; issue aL,b01(u+1) from
//          bufn; stage B-n2,n3(u+2)->bufc; BAR (tile end)
// Staging legality (write-after-read, via the 3 retained barriers):
//   aL-LDS (A-n0,n2 of bufc): reads issued P4(u-1), executed before each
//     wave's Q1 MFMA (compiler wait) -> all waves by P1-end BAR -> P2 stage ok.
//   B-LDS: b01 reads executed before Q1 (P1), b23 before Q2 (P2) -> all by
//     P2-end BAR -> P3/P4 stages ok.
//   aH-LDS (A-n1,n3 of bufc): reads executed before Q3 (P3) -> all by tile-end
//     BAR -> P1(u+1)'s stage (same regions of buf[(u+2)&1]=bufc... next tile's
//     bufn) ok.
// vmcnt(4) at P4(u): outstanding <= P2(u-1..)'s; precisely: all 8 stages of
// buf[u+1] (issued P2(u-1)..P1(u)) are older than P2(u),P3(u)'s 4 -> waiting
// to 4 proves buf[u+1] fully landed; tile u+2's 4 stay in flight. The asm has
// a "memory" clobber so the bufn fragment loads cannot hoist above it.
// All stages in flight target the OTHER buffer than any concurrent reads.
// Per-acc K order: tiles ascending, kk0->kk1 per quadrant -> bit-identical.
// LDS layout per matrix: 256 rows x 8 chunks of 16B, phys_chunk = c ^ (r&7);
// staging region n = rows [64n,64n+64) = 1 gl_lds16/thread; fragment reads
// ra*128 + ((q^(ra&7))*16), kk=1 = ^64 (uniform bank spread, ~0 conflicts).
// Split-K / batch: abz = bz & abmask; kbase = (bz >> kshift) * K.
// B batched via sBb (final GEMM: G' = [4][1024][1024]).
// TRANS_OUT epilogue: two 128-col passes through sT[128][264] (fits LDS);
// its leading __syncthreads() drains all counters (incl. pending DMA).
template<int EPI, bool TRANS_OUT>
__global__ __launch_bounds__(512, 2)
void gemm_bt256(const u16* __restrict__ Ap, const u16* __restrict__ Bp0,
                const float* __restrict__ bias, const float* __restrict__ Zall,
                void* __restrict__ Cp,
                int M, int N, int K, int ldA, int ldB, int ldC,
                long sAb, long sBb, long sCb, long sZb, int abmask, int kshift)
{
  constexpr int TSTRIDE = 65536;                  // one K-tile buffer (A+B)
  constexpr int BOFF    = 32768;                  // B tile offset within buffer
  __shared__ char smem[2 * TSTRIDE];              // 128 KB -> 1 block/CU

  const int tid  = threadIdx.x;
  const int lane = tid & 63;
  const int wave = tid >> 6;
  const int wm = wave >> 2, wn = wave & 3;   // 2x4 waves, 128x64 each
  const int fl = lane & 15;
  const int q  = lane >> 4;
  const int r4 = q * 4;
  const int bm0 = blockIdx.x * 256, bn0 = blockIdx.y * 256;
  const int bz = blockIdx.z;
  const int abz = bz & abmask;
  const int kbase = (bz >> kshift) * K;

  const u16* Ah = Ap  + (size_t)abz * sAb + kbase;
  const u16* Bh = Bp0 + (size_t)abz * sBb + kbase;

  // staging: per matrix 2048 16B slots (256 rows x 8 chunks); region n =
  // slots [512n, 512(n+1)) = rows [64n, 64n+64); one gl_lds16/thread/region.
  const u16* gA[4]; const u16* gB[4]; int sL[4];
  #pragma unroll
  for (int n = 0; n < 4; ++n) {
    int j = n * 512 + tid;                   // physical 16B slot
    int R = j >> 3, c = (j & 7) ^ (R & 7);
    gA[n] = Ah + (size_t)(bm0 + R) * ldA + c * 8;
    gB[n] = Bh + (size_t)(bn0 + R) * ldB + c * 8;
    sL[n] = (n * 512 + wave * 64) * 16;
  }

  // fragment LDS byte offsets (kk=0; kk=1 = ^64)
  int aoff[8], boff[4];
  #pragma unroll
  for (int i = 0; i < 8; ++i) {
    int ra = wm * 128 + i * 16 + fl;
    aoff[i] = ra * 128 + ((q ^ (ra & 7)) * 16);
  }
  #pragma unroll
  for (int i = 0; i < 4; ++i) {
    int rb = wn * 64 + i * 16 + fl;
    boff[i] = rb * 128 + ((q ^ (rb & 7)) * 16);
  }

  floatx4 zero = {0.f, 0.f, 0.f, 0.f};
  floatx4 acc[8][4];
  #pragma unroll
  for (int i = 0; i < 8; ++i)
    #pragma unroll
    for (int j = 0; j < 4; ++j) acc[i][j] = zero;

  auto stA = [&](int t, int n) {             // stage A region n of tile t
    gl_lds16(gA[n] + t * 64, smem + (t & 1) * TSTRIDE + sL[n]);
  };
  auto stB = [&](int t, int n) {             // stage B region n of tile t
    gl_lds16(gB[n] + t * 64, smem + (t & 1) * TSTRIDE + BOFF + sL[n]);
  };

  const int NT = K >> 6;                     // 16 (K=1024) or 4 (G, K=256)
  // prologue: tile0 all 8 regions + tile1's 6 (A-n1,n3 come at P1(0))
  #pragma unroll
  for (int n = 0; n < 4; ++n) stA(0, n);
  #pragma unroll
  for (int n = 0; n < 4; ++n) stB(0, n);
  if (NT > 1) {
    stA(1, 0); stA(1, 2);
    stB(1, 0); stB(1, 1); stB(1, 2); stB(1, 3);
    asm volatile("s_waitcnt vmcnt(6)" ::: "memory");   // tile0 landed
  } else {
    asm volatile("s_waitcnt vmcnt(0)" ::: "memory");
  }
  __builtin_amdgcn_s_barrier();

  short8 aL[8], aH[8], b01[4], b23[4];       // static-indexed reg sets
  // pre-issue Q1(0) fragments (aL, b01 from buf0)
  #pragma unroll
  for (int i = 0; i < 4; ++i) {
    aL[2 * i]     = *(const short8*)(smem + aoff[i]);
    aL[2 * i + 1] = *(const short8*)(smem + (aoff[i] ^ 64));
  }
  #pragma unroll
  for (int i = 0; i < 2; ++i) {
    b01[2 * i]     = *(const short8*)(smem + BOFF + boff[i]);
    b01[2 * i + 1] = *(const short8*)(smem + BOFF + (boff[i] ^ 64));
  }

  for (int u = 0; u < NT; ++u) {
    const bool pf1 = u + 1 < NT;
    const bool pf2 = u + 2 < NT;
    const char* bufc = smem + (u & 1) * TSTRIDE;
    const char* bufn = smem + ((u + 1) & 1) * TSTRIDE;

    // ---- P1: issue b23(u); stage A-n1,n3(u+1); MFMA Q1 (aL x b01); BAR ----
    #pragma unroll
    for (int i = 0; i < 2; ++i) {
      b23[2 * i]     = *(const short8*)(bufc + BOFF + boff[i + 2]);
      b23[2 * i + 1] = *(const short8*)(bufc + BOFF + (boff[i + 2] ^ 64));
    }
    if (pf1) { stA(u + 1, 1); stA(u + 1, 3); }
    __builtin_amdgcn_s_setprio(1);
    #pragma unroll
    for (int kk = 0; kk < 2; ++kk)
      #pragma unroll
      for (int mi = 0; mi < 4; ++mi)
        #pragma unroll
        for (int ni = 0; ni < 2; ++ni)
          acc[mi][ni] = __builtin_amdgcn_mfma_f32_16x16x32_bf16(
              aL[2 * mi + kk], b01[2 * ni + kk], acc[mi][ni], 0, 0, 0);
    __builtin_amdgcn_s_setprio(0);
    __builtin_amdgcn_s_barrier();

    // ---- P2: issue aH(u); stage A-n0,n2(u+2); MFMA Q2 (aL x b23); BAR ----
    #pragma unroll
    for (int i = 0; i < 4; ++i) {
      aH[2 * i]     = *(const short8*)(bufc + aoff[i + 4]);
      aH[2 * i + 1] = *(const short8*)(bufc + (aoff[i + 4] ^ 64));
    }
    if (pf2) { stA(u + 2, 0); stA(u + 2, 2); }
    __builtin_amdgcn_s_setprio(1);
    #pragma unroll
    for (int kk = 0; kk < 2; ++kk)
      #pragma unroll
      for (int mi = 0; mi < 4; ++mi)
        #pragma unroll
        for (int ni = 0; ni < 2; ++ni)
          acc[mi][ni + 2] = __builtin_amdgcn_mfma_f32_16x16x32_bf16(
              aL[2 * mi + kk], b23[2 * ni + kk], acc[mi][ni + 2], 0, 0, 0);
    __builtin_amdgcn_s_setprio(0);
    __builtin_amdgcn_s_barrier();

    // ---- P3: stage B-n0,n1(u+2); MFMA Q3 (aH x b23) ----
    if (pf2) { stB(u + 2, 0); stB(u + 2, 1); }
    __builtin_amdgcn_s_setprio(1);
    #pragma unroll
    for (int kk = 0; kk < 2; ++kk)
      #pragma unroll
      for (int mi = 0; mi < 4; ++mi)
        #pragma unroll
        for (int ni = 0; ni < 2; ++ni)
          acc[mi + 4][ni + 2] = __builtin_amdgcn_mfma_f32_16x16x32_bf16(
              aH[2 * mi + kk], b23[2 * ni + kk], acc[mi + 4][ni + 2], 0, 0, 0);
    __builtin_amdgcn_s_setprio(0);

    // ---- P4: MFMA Q4 (aH x b01); vmcnt; issue Q1(u+1); stage B-n2,n3; BAR --
    __builtin_amdgcn_s_setprio(1);
    #pragma unroll
    for (int kk = 0; kk < 2; ++kk)
      #pragma unroll
      for (int mi = 0; mi < 4; ++mi)
        #pragma unroll
        for (int ni = 0; ni < 2; ++ni)
          acc[mi + 4][ni] = __builtin_amdgcn_mfma_f32_16x16x32_bf16(
              aH[2 * mi + kk], b01[2 * ni + kk], acc[mi + 4][ni], 0, 0, 0);
    __builtin_amdgcn_s_setprio(0);
    if (pf1) {
      if (pf2) asm volatile("s_waitcnt vmcnt(4)" ::: "memory");
      else     asm volatile("s_waitcnt vmcnt(0)" ::: "memory");
      #pragma unroll
      for (int i = 0; i < 4; ++i) {
        aL[2 * i]     = *(const short8*)(bufn + aoff[i]);
        aL[2 * i + 1] = *(const short8*)(bufn + (aoff[i] ^ 64));
      }
      #pragma unroll
      for (int i = 0; i < 2; ++i) {
        b01[2 * i]     = *(const short8*)(bufn + BOFF + boff[i]);
        b01[2 * i + 1] = *(const short8*)(bufn + BOFF + (boff[i] ^ 64));
      }
      if (pf2) { stB(u + 2, 2); stB(u + 2, 3); }
      __builtin_amdgcn_s_barrier();
    }
  }

  if constexpr (!TRANS_OUT) {
    #pragma unroll
    for (int mi = 0; mi < 8; ++mi) {
      #pragma unroll
      for (int ni = 0; ni < 4; ++ni) {
        int col = bn0 + wn * 64 + ni * 16 + fl;
        #pragma unroll
        for (int r = 0; r < 4; ++r) {
          int row = bm0 + wm * 128 + mi * 16 + r4 + r;
          float vv = acc[mi][ni][r];
          if constexpr (EPI == EPI_PHI_BIAS) {
            vv += bias[col];
            vv = __expf(-0.5f * vv * vv);
          }
          if constexpr (EPI == EPI_ZBIAS_F32)
            vv = vv * Zall[(size_t)abz * sZb + row] + bias[col];
          if constexpr (EPI == EPI_ZBIAS_F32)
            ((float*)Cp)[(size_t)bz * sCb + (size_t)row * ldC + col] = vv;
          else
            ((u16*)Cp)[(size_t)bz * sCb + (size_t)row * ldC + col] = f2b(vv);
        }
      }
    }
  } else {
    // two passes of 128 d-cols through sT[128][264]; coalesced 16B stores
    // into C = [4][N(d)][4096(t)] bf16 (256-row tile never crosses a batch).
    u16* sT = (u16*)smem;                    // 128*264*2 = 67584 <= 128K
    #pragma unroll
    for (int p = 0; p < 2; ++p) {
      __syncthreads();                       // p=0: drains K-loop (all cnts)
      if ((wn >> 1) == p) {
        #pragma unroll
        for (int mi = 0; mi < 8; ++mi) {
          #pragma unroll
          for (int ni = 0; ni < 4; ++ni) {
            int colL = wn * 64 + ni * 16 + fl;       // in [p*128, p*128+128)
            int row0 = wm * 128 + mi * 16 + r4;
            float bcol = bias[bn0 + colL];
            ushort4 h;
            #pragma unroll
            for (int r = 0; r < 4; ++r) {
              float vv = acc[mi][ni][r] + bcol;
              if constexpr (EPI == EPI_PHI_BIAS) vv = __expf(-0.5f * vv * vv);
              ((u16*)&h)[r] = f2b(vv);
            }
            *(ushort4*)(sT + (colL - p * 128) * 264 + row0) = h;
          }
        }
      }
      __syncthreads();
      #pragma unroll
      for (int i = 0; i < 8; ++i) {
        int c = tid + i * 512;               // 4096 x 16B chunks
        int dloc = c >> 5, t8 = (c & 31) * 8;
        int4 vv = *(const int4*)(sT + dloc * 264 + t8);
        int gd = bn0 + p * 128 + dloc;
        int gt = bm0 + t8;
        int batch = gt >> 12, tt = gt & 4095;
        *(int4*)((u16*)Cp + ((size_t)batch * N + gd) * 4096 + tt) = vv;
      }
    }
  }
}

// fp32 -> bf16 (RNE), 16M elems, 8 per thread, 16B stores. grid 8192x256.
__global__ __launch_bounds__(256)
void fcvt(const float* __restrict__ src, u16* __restrict__ dst) {
  size_t i = ((size_t)blockIdx.x * 256 + threadIdx.x) * 8;
  float4 a = *(const float4*)(src + i);
  float4 b = *(const float4*)(src + i + 4);
  union { ushort4 h[2]; int4 v; } o;
  o.h[0].x = f2b(a.x); o.h[0].y = f2b(a.y); o.h[0].z = f2b(a.z); o.h[0].w = f2b(a.w);
  o.h[1].x = f2b(b.x); o.h[1].y = f2b(b.y); o.h[1].z = f2b(b.z); o.h[1].w = f2b(b.w);
  *(int4*)(dst + i) = o.v;
}

__global__ __launch_bounds__(256)
void wconv(const float* __restrict__ w0, const float* __restrict__ w1,
           const float* __restrict__ w2, const float* __restrict__ w3,
           u16* __restrict__ dst) {
  unsigned e = blockIdx.x * 256 + threadIdx.x;
  int mat = e >> 18;
  size_t off = (size_t)(e & 262143) * 4;
  const float* src = mat == 0 ? w0 : mat == 1 ? w1 : mat == 2 ? w2 : w3;
  float4 v = *(const float4*)(src + off);
  ushort4 h;
  h.x = f2b(v.x); h.y = f2b(v.y); h.z = f2b(v.z); h.w = f2b(v.w);
  *(ushort4*)(dst + (size_t)mat * 1048576 + off) = h;
}

// out[i] = round(sum over 4 K-slices of bf16 partials), 4M elems, slice stride 4M
__global__ __launch_bounds__(256)
void reduce4(const u16* __restrict__ P, u16* __restrict__ out) {
  size_t i = ((size_t)blockIdx.x * 256 + threadIdx.x) * 8;
  int4 a = *(const int4*)(P + i);
  int4 b = *(const int4*)(P + i + 4194304);
  int4 c = *(const int4*)(P + i + 8388608);
  int4 d = *(const int4*)(P + i + 12582912);
  const u16* ha = (const u16*)&a; const u16* hb = (const u16*)&b;
  const u16* hc = (const u16*)&c; const u16* hd = (const u16*)&d;
  ushort4 o0, o1;
  #pragma unroll
  for (int j = 0; j < 8; ++j) {
    float s = b2f(ha[j]) + b2f(hb[j]) + b2f(hc[j]) + b2f(hd[j]);
    ((u16*)(j < 4 ? &o0 : &o1))[j & 3] = f2b(s);
  }
  *(ushort4*)(out + i) = o0;
  *(ushort4*)(out + i + 4) = o1;
}

// Ksum[b*1024+d] = sum_t KT[b][d][t]; one wave per (b,d) row
__global__ __launch_bounds__(256)
void ksum_rows(const u16* __restrict__ KT, float* __restrict__ Ksum) {
  int lane = threadIdx.x & 63;
  int row = blockIdx.x * 4 + (threadIdx.x >> 6);
  const u16* p = KT + (size_t)row * 4096;
  float s = 0.f;
  #pragma unroll
  for (int i = 0; i < 8; ++i) {
    int4 d = *(const int4*)(p + i * 512 + lane * 8);
    const u16* h = (const u16*)&d;
    #pragma unroll
    for (int j = 0; j < 8; ++j) s += b2f(h[j]);
  }
  #pragma unroll
  for (int off = 32; off; off >>= 1) s += __shfl_xor(s, off, 64);
  if (lane == 0) Ksum[row] = s;
}

// Z[t] = 1/(Q[t,:]·Ksum[batch,:] + 1e-6); one wave per token
__global__ __launch_bounds__(256)
void zden(const u16* __restrict__ Qb, const float* __restrict__ Ksum,
          float* __restrict__ Z) {
  int lane = threadIdx.x & 63;
  int t = blockIdx.x * 4 + (threadIdx.x >> 6);
  const u16* qp = Qb + (size_t)t * 1024;
  const float* ks = Ksum + (size_t)(t >> 12) * 1024;
  float s = 0.f;
  #pragma unroll
  for (int i = 0; i < 2; ++i) {
    int idx = i * 512 + lane * 8;
    int4 d = *(const int4*)(qp + idx);
    const u16* h = (const u16*)&d;
    float4 k0 = *(const float4*)(ks + idx);
    float4 k1 = *(const float4*)(ks + idx + 4);
    s += b2f(h[0]) * k0.x + b2f(h[1]) * k0.y + b2f(h[2]) * k0.z + b2f(h[3]) * k0.w
       + b2f(h[4]) * k1.x + b2f(h[5]) * k1.y + b2f(h[6]) * k1.z + b2f(h[7]) * k1.w;
  }
  #pragma unroll
  for (int off = 32; off; off >>= 1) s += __shfl_xor(s, off, 64);
  if (lane == 0) Z[t] = 1.0f / (s + 1e-6f);
}

extern "C" void kernel_launch(void* const* d_in, const int* in_sizes, int n_in,
                              void* d_out, int out_size, void* d_ws, size_t ws_size,
                              hipStream_t stream) {
  const float* q  = (const float*)d_in[0];
  const float* k  = (const float*)d_in[1];
  const float* v  = (const float*)d_in[2];
  const float* Wq = (const float*)d_in[3];
  const float* bq = (const float*)d_in[4];
  const float* Wk = (const float*)d_in[5];
  const float* bk = (const float*)d_in[6];
  const float* Wv = (const float*)d_in[7];
  const float* bv = (const float*)d_in[8];
  const float* Wo = (const float*)d_in[9];
  const float* bo = (const float*)d_in[10];
  float* out = (float*)d_out;

  // workspace layout (~112.1 MiB), aliasing chain (stream-ordered, see steps):
  u16* Wqb = (u16*)d_ws;                 // 4x 1024x1024 bf16 = 8 MiB
  u16* Wkb = Wqb + 1048576;
  u16* Wvb = Wkb + 1048576;
  u16* Wob = Wvb + 1048576;
  u16* Qb  = Wob + 1048576;              // [16384][1024] bf16, 32 MiB
  u16* KT  = Qb  + 16777216;             // [4][1024][4096] bf16, 32 MiB
  u16* VT  = KT  + 16777216;             // [4][1024][4096] bf16, 32 MiB
  u16* KVr = VT  + 16777216;             // [4][1024(d)][1024(l)] bf16, 8 MiB
  float* Ksum = (float*)(KVr + 4194304); // [4][1024] f32
  float* Z    = Ksum + 4096;             // [16384] f32
  // region reuse (each write strictly after the prior reader finishes):
  u16* kb16 = Qb;   // bf16 k input; dead after Kproj
  u16* vb16 = Qb;   // bf16 v input (overwrites kb16); dead after Vproj
  u16* Pkv  = Qb;   // S2 split-K partials (overwrites vb16); dead after reduce4
  u16* Pg   = VT;   // G split-K partials (VT dead after S2)
  u16* Gp   = KT;   // G' [4][1024(n)][1024(d)] (KT dead after S2)
  u16* qb16 = VT;   // bf16 q input (Pg dead after its reduce4); dead after Qproj

  // 1. weights + k input -> bf16
  wconv<<<4096, 256, 0, stream>>>(Wq, Wk, Wv, Wo, Wqb);
  fcvt<<<8192, 256, 0, stream>>>(k, kb16);

  // 2. K projection: KT[b][d][t] = phi(k Wk^T + bk), transposed out
  dim3 gp(64, 4, 1);
  gemm_bt256<EPI_PHI_BIAS, true><<<gp, 512, 0, stream>>>(
      kb16, Wkb, bk, nullptr, KT, 16384, 1024, 1024, 1024, 1024, 0,
      0, 0, 0, 0, 0, 2);
  ksum_rows<<<1024, 256, 0, stream>>>(KT, Ksum);

  // 3. V projection (vb16 overwrites kb16 region; Kproj done)
  fcvt<<<8192, 256, 0, stream>>>(v, vb16);
  gemm_bt256<EPI_BIAS, true><<<gp, 512, 0, stream>>>(
      vb16, Wvb, bv, nullptr, VT, 16384, 1024, 1024, 1024, 1024, 0,
      0, 0, 0, 0, 0, 2);

  // 4. S2: KVr[d,l] = sum_t KT[d,t]*VT[l,t], split-K x4 (z = kslice*4+batch)
  dim3 g2(4, 4, 16);
  gemm_bt256<EPI_NONE, false><<<g2, 512, 0, stream>>>(
      KT, VT, nullptr, nullptr, Pkv, 1024, 1024, 1024, 4096, 4096, 1024,
      4194304L, 4194304L, 1048576L, 0, 3, 2);
  reduce4<<<2048, 256, 0, stream>>>(Pkv, KVr);

  // 5. G'[n,d] = sum_l Wob[n,l]*KVr[d,l], split-K x4 (K=256/slice).
  //    Runs BEFORE Q projection so qb16 can take the VT region afterwards.
  dim3 gg(4, 4, 16);
  gemm_bt256<EPI_NONE, false><<<gg, 512, 0, stream>>>(
      Wob, KVr, nullptr, nullptr, Pg, 1024, 1024, 256, 1024, 1024, 1024,
      0L, 1048576L, 1048576L, 0, 3, 2);
  reduce4<<<2048, 256, 0, stream>>>(Pg, Gp);

  // 6. Q projection (qb16 overwrites Pg region; its reduce4 done)
  fcvt<<<8192, 256, 0, stream>>>(q, qb16);
  gemm_bt256<EPI_PHI_BIAS, false><<<gp, 512, 0, stream>>>(
      qb16, Wqb, bq, nullptr, Qb, 16384, 1024, 1024, 1024, 1024, 1024,
      0, 0, 0, 0, 0, 2);
  zden<<<4096, 256, 0, stream>>>(Qb, Ksum, Z);

  // 7. final: out[t,n] = Z[t]*(sum_d Qb[t,d]*G'[n,d]) + bo[n], fp32 out
  dim3 gf(16, 4, 4);
  gemm_bt256<EPI_ZBIAS_F32, false><<<gf, 512, 0, stream>>>(
      Qb, Gp, bo, Z, out, 4096, 1024, 1024, 1024, 1024, 1024,
      4194304L, 1048576L, 4194304L, 4096L, 3, 2);
}

// Round 14
// 289.182 us; speedup vs baseline: 1.0998x; 1.0998x over previous
//
#include <hip/hip_runtime.h>

typedef unsigned short u16;
typedef unsigned int u32;
typedef unsigned long long u64;

typedef __attribute__((ext_vector_type(8))) short short8;   // 8 bf16 = 4 VGPRs
typedef __attribute__((ext_vector_type(4))) float floatx4;  // MFMA accumulator

__device__ __forceinline__ float b2f(u16 h) {
  u32 u = ((u32)h) << 16;
  return __builtin_bit_cast(float, u);
}
__device__ __forceinline__ u16 f2b(float f) {
  u32 u = __builtin_bit_cast(u32, f);
  u32 r = 0x7FFFu + ((u >> 16) & 1u);  // RNE
  return (u16)((u + r) >> 16);
}

// async global->LDS, 16B per lane. LDS dest = wave-uniform base + lane*16.
__device__ __forceinline__ void gl_lds16(const void* g, void* l) {
  __builtin_amdgcn_global_load_lds(
      (__attribute__((address_space(1))) void*)(u64)g,
      (__attribute__((address_space(3))) void*)(u32)(u64)l, 16, 0, 0);
}

enum { EPI_PHI_BIAS = 0, EPI_BIAS = 1, EPI_NONE = 2,
       EPI_ZBIAS_F32 = 3 };

// ==================== 256x256 kernel (ALL GEMMs) =============================
// R10-best structure (301us): 256x256 tile, 8 waves (2M x 4N, 128x64 each,
// acc[8][4]), BK=64 K-tiles, 128B-contiguous staging rows, 2 x 64KB LDS
// buffers, 2 kstep/tile, ONE barrier per tile. Schedule variants R9/R11/R12/
// R13 (phase splits, counted vmcnt, prefetch re-pipelining) were all null or
// regressions -> reverted to this.
// R14: A_F32 path fuses the fp32->bf16 input conversion INTO A-staging,
// deleting the 3 standalone fcvt passes (96MB HBM each, ~48us total):
//   tile top: issue 8x float4 A(t+1) loads (rows = 128B fp32 x2 segments,
//   block-cooperative, each element once) + 4x B gl_lds16 DMA.
//   after kstep(kk0) (~1250cy, covers HBM latency): truncate-pack rA
//   (v_perm 0x07060302, the R0-R3-proven truncation; absmax unchanged) and
//   ds_write_b128 into buf^1's swizzled A layout. Compiler emits counted
//   vmcnt for rA deps; end-of-tile lgkmcnt(0) fences the ds_writes.
//   Write-after-read: buf^1's readers (tile t-1) drained at the t-1 barrier.
// LDS layout per matrix: 256 rows x 8 chunks of 16B, phys_chunk = c ^ (r&7);
// staging slot j: R=j>>3, c=(j&7)^(R&7); fragment reads ra*128+((q^(ra&7))*16),
// kk=1 = ^64 (uniform bank spread).
// Split-K / batch: abz = bz & abmask; kbase = (bz >> kshift) * K.
// B batched via sBb (final GEMM: G' = [4][1024][1024]).
// TRANS_OUT epilogue: two 128-col passes through sT[128][264] (fits LDS).
template<int EPI, bool TRANS_OUT, bool A_F32>
__global__ __launch_bounds__(512, 2)
void gemm_bt256(const void* __restrict__ Ap, const u16* __restrict__ Bp0,
                const float* __restrict__ bias, const float* __restrict__ Zall,
                void* __restrict__ Cp,
                int M, int N, int K, int ldA, int ldB, int ldC,
                long sAb, long sBb, long sCb, long sZb, int abmask, int kshift)
{
  constexpr int TSTRIDE = 65536;                  // one K-tile buffer (A+B)
  constexpr int BOFF    = 32768;                  // B tile offset within buffer
  __shared__ char smem[2 * TSTRIDE];              // 128 KB -> 1 block/CU

  const int tid  = threadIdx.x;
  const int lane = tid & 63;
  const int wave = tid >> 6;
  const int wm = wave >> 2, wn = wave & 3;   // 2x4 waves, 128x64 each
  const int fl = lane & 15;
  const int q  = lane >> 4;
  const int r4 = q * 4;
  const int bm0 = blockIdx.x * 256, bn0 = blockIdx.y * 256;
  const int bz = blockIdx.z;
  const int abz = bz & abmask;
  const int kbase = (bz >> kshift) * K;

  const u16*   Ah = (const u16*)Ap   + (size_t)abz * sAb + kbase;
  const float* Af = (const float*)Ap + (size_t)abz * sAb + kbase;
  const u16*   Bh = Bp0 + (size_t)abz * sBb + kbase;

  // staging: per matrix 2048 16B LDS slots (256 rows x 8 swizzled chunks).
  const u16* gA[4]; const float* gAf[4]; const u16* gB[4]; int sL[4], dL[4];
  #pragma unroll
  for (int n = 0; n < 4; ++n) {
    int j = n * 512 + tid;                   // physical 16B slot
    int R = j >> 3, c = (j & 7) ^ (R & 7);
    if constexpr (A_F32) gAf[n] = Af + (size_t)(bm0 + R) * ldA + c * 8;
    else                 gA[n]  = Ah + (size_t)(bm0 + R) * ldA + c * 8;
    gB[n] = Bh + (size_t)(bn0 + R) * ldB + c * 8;
    sL[n] = (n * 512 + wave * 64) * 16;      // wave-uniform base (gl_lds)
    dL[n] = j * 16;                          // per-thread ds_write dest
  }

  // fragment LDS byte offsets (kk=0; kk=1 = ^64)
  int aoff[8], boff[4];
  #pragma unroll
  for (int i = 0; i < 8; ++i) {
    int ra = wm * 128 + i * 16 + fl;
    aoff[i] = ra * 128 + ((q ^ (ra & 7)) * 16);
  }
  #pragma unroll
  for (int i = 0; i < 4; ++i) {
    int rb = wn * 64 + i * 16 + fl;
    boff[i] = rb * 128 + ((q ^ (rb & 7)) * 16);
  }

  floatx4 zero = {0.f, 0.f, 0.f, 0.f};
  floatx4 acc[8][4];
  #pragma unroll
  for (int i = 0; i < 8; ++i)
    #pragma unroll
    for (int j = 0; j < 4; ++j) acc[i][j] = zero;

  auto stageB = [&](int t, char* base) {     // 4 gl_lds16, 128B rows
    #pragma unroll
    for (int n = 0; n < 4; ++n) gl_lds16(gB[n] + t * 64, base + BOFF + sL[n]);
  };
  auto stageA_dma = [&](int t, char* base) { // bf16-A path
    #pragma unroll
    for (int n = 0; n < 4; ++n) gl_lds16(gA[n] + t * 64, base + sL[n]);
  };

  float4 rA[8];                              // fp32-A path: in-flight A rows
  auto loadA = [&](int t) {
    #pragma unroll
    for (int n = 0; n < 4; ++n) {
      rA[2 * n]     = *(const float4*)(gAf[n] + t * 64);
      rA[2 * n + 1] = *(const float4*)(gAf[n] + t * 64 + 4);
    }
  };
  auto packA = [&](char* base) {             // truncate-pack (R1-proven)
    #pragma unroll
    for (int n = 0; n < 4; ++n) {
      const u32* xb = (const u32*)&rA[2 * n];
      const u32* yb = (const u32*)&rA[2 * n + 1];
      union { u32 w[4]; short8 s; } cv;
      cv.w[0] = __builtin_amdgcn_perm(xb[1], xb[0], 0x07060302u);
      cv.w[1] = __builtin_amdgcn_perm(xb[3], xb[2], 0x07060302u);
      cv.w[2] = __builtin_amdgcn_perm(yb[1], yb[0], 0x07060302u);
      cv.w[3] = __builtin_amdgcn_perm(yb[3], yb[2], 0x07060302u);
      *(short8*)(base + dL[n]) = cv.s;
    }
  };

  auto kstep = [&](const char* bufc, int xo) {  // xo = 0 (kk=0) or 64 (kk=1)
    short8 bF[4], aF[8];
    #pragma unroll
    for (int i = 0; i < 4; ++i) bF[i] = *(const short8*)(bufc + BOFF + (boff[i] ^ xo));
    #pragma unroll
    for (int i = 0; i < 8; ++i) aF[i] = *(const short8*)(bufc + (aoff[i] ^ xo));
    __builtin_amdgcn_s_setprio(1);
    #pragma unroll
    for (int mi = 0; mi < 8; ++mi)
      #pragma unroll
      for (int ni = 0; ni < 4; ++ni)
        acc[mi][ni] = __builtin_amdgcn_mfma_f32_16x16x32_bf16(
            aF[mi], bF[ni], acc[mi][ni], 0, 0, 0);
    __builtin_amdgcn_s_setprio(0);
  };

  const int NT = K >> 6;                     // 16 (K=1024) or 4 (G, K=256)
  if constexpr (A_F32) {
    loadA(0); stageB(0, smem);
    asm volatile("s_waitcnt vmcnt(4)" ::: "memory");   // 8 A loads (oldest)
    packA(smem);
    asm volatile("s_waitcnt vmcnt(0) lgkmcnt(0)\ns_barrier" ::: "memory");
    int cur = 0;
    for (int t = 0; t < NT; ++t) {
      const bool pf = t + 1 < NT;
      const char* bufc = smem + cur;
      char* bufn = smem + (cur ^ TSTRIDE);
      if (pf) { loadA(t + 1); stageB(t + 1, bufn); }
      kstep(bufc, 0);
      if (pf) packA(bufn);                   // compiler waits rA deps (counted)
      kstep(bufc, 64);
      if (pf)
        asm volatile("s_waitcnt vmcnt(0) lgkmcnt(0)\ns_barrier" ::: "memory");
      cur ^= TSTRIDE;
    }
  } else {
    stageA_dma(0, smem); stageB(0, smem);
    asm volatile("s_waitcnt vmcnt(0)\ns_barrier" ::: "memory");
    int cur = 0;
    for (int t = 0; t < NT; ++t) {
      if (t + 1 < NT) {
        stageA_dma(t + 1, smem + (cur ^ TSTRIDE));
        stageB(t + 1, smem + (cur ^ TSTRIDE));
      }
      const char* bufc = smem + cur;
      kstep(bufc, 0);
      kstep(bufc, 64);
      if (t + 1 < NT)
        asm volatile("s_waitcnt vmcnt(0) lgkmcnt(0)\ns_barrier" ::: "memory");
      cur ^= TSTRIDE;
    }
  }

  if constexpr (!TRANS_OUT) {
    #pragma unroll
    for (int mi = 0; mi < 8; ++mi) {
      #pragma unroll
      for (int ni = 0; ni < 4; ++ni) {
        int col = bn0 + wn * 64 + ni * 16 + fl;
        #pragma unroll
        for (int r = 0; r < 4; ++r) {
          int row = bm0 + wm * 128 + mi * 16 + r4 + r;
          float vv = acc[mi][ni][r];
          if constexpr (EPI == EPI_PHI_BIAS) {
            vv += bias[col];
            vv = __expf(-0.5f * vv * vv);
          }
          if constexpr (EPI == EPI_ZBIAS_F32)
            vv = vv * Zall[(size_t)abz * sZb + row] + bias[col];
          if constexpr (EPI == EPI_ZBIAS_F32)
            ((float*)Cp)[(size_t)bz * sCb + (size_t)row * ldC + col] = vv;
          else
            ((u16*)Cp)[(size_t)bz * sCb + (size_t)row * ldC + col] = f2b(vv);
        }
      }
    }
  } else {
    // two passes of 128 d-cols through sT[128][264]; coalesced 16B stores
    // into C = [4][N(d)][4096(t)] bf16 (256-row tile never crosses a batch).
    u16* sT = (u16*)smem;                    // 128*264*2 = 67584 <= 128K
    #pragma unroll
    for (int p = 0; p < 2; ++p) {
      __syncthreads();                       // p=0: drains K-loop (all cnts)
      if ((wn >> 1) == p) {
        #pragma unroll
        for (int mi = 0; mi < 8; ++mi) {
          #pragma unroll
          for (int ni = 0; ni < 4; ++ni) {
            int colL = wn * 64 + ni * 16 + fl;       // in [p*128, p*128+128)
            int row0 = wm * 128 + mi * 16 + r4;
            float bcol = bias[bn0 + colL];
            ushort4 h;
            #pragma unroll
            for (int r = 0; r < 4; ++r) {
              float vv = acc[mi][ni][r] + bcol;
              if constexpr (EPI == EPI_PHI_BIAS) vv = __expf(-0.5f * vv * vv);
              ((u16*)&h)[r] = f2b(vv);
            }
            *(ushort4*)(sT + (colL - p * 128) * 264 + row0) = h;
          }
        }
      }
      __syncthreads();
      #pragma unroll
      for (int i = 0; i < 8; ++i) {
        int c = tid + i * 512;               // 4096 x 16B chunks
        int dloc = c >> 5, t8 = (c & 31) * 8;
        int4 vv = *(const int4*)(sT + dloc * 264 + t8);
        int gd = bn0 + p * 128 + dloc;
        int gt = bm0 + t8;
        int batch = gt >> 12, tt = gt & 4095;
        *(int4*)((u16*)Cp + ((size_t)batch * N + gd) * 4096 + tt) = vv;
      }
    }
  }
}

__global__ __launch_bounds__(256)
void wconv(const float* __restrict__ w0, const float* __restrict__ w1,
           const float* __restrict__ w2, const float* __restrict__ w3,
           u16* __restrict__ dst) {
  unsigned e = blockIdx.x * 256 + threadIdx.x;
  int mat = e >> 18;
  size_t off = (size_t)(e & 262143) * 4;
  const float* src = mat == 0 ? w0 : mat == 1 ? w1 : mat == 2 ? w2 : w3;
  float4 v = *(const float4*)(src + off);
  ushort4 h;
  h.x = f2b(v.x); h.y = f2b(v.y); h.z = f2b(v.z); h.w = f2b(v.w);
  *(ushort4*)(dst + (size_t)mat * 1048576 + off) = h;
}

// out[i] = round(sum over 4 K-slices of bf16 partials), 4M elems, slice stride 4M
__global__ __launch_bounds__(256)
void reduce4(const u16* __restrict__ P, u16* __restrict__ out) {
  size_t i = ((size_t)blockIdx.x * 256 + threadIdx.x) * 8;
  int4 a = *(const int4*)(P + i);
  int4 b = *(const int4*)(P + i + 4194304);
  int4 c = *(const int4*)(P + i + 8388608);
  int4 d = *(const int4*)(P + i + 12582912);
  const u16* ha = (const u16*)&a; const u16* hb = (const u16*)&b;
  const u16* hc = (const u16*)&c; const u16* hd = (const u16*)&d;
  ushort4 o0, o1;
  #pragma unroll
  for (int j = 0; j < 8; ++j) {
    float s = b2f(ha[j]) + b2f(hb[j]) + b2f(hc[j]) + b2f(hd[j]);
    ((u16*)(j < 4 ? &o0 : &o1))[j & 3] = f2b(s);
  }
  *(ushort4*)(out + i) = o0;
  *(ushort4*)(out + i + 4) = o1;
}

// Ksum[b*1024+d] = sum_t KT[b][d][t]; one wave per (b,d) row
__global__ __launch_bounds__(256)
void ksum_rows(const u16* __restrict__ KT, float* __restrict__ Ksum) {
  int lane = threadIdx.x & 63;
  int row = blockIdx.x * 4 + (threadIdx.x >> 6);
  const u16* p = KT + (size_t)row * 4096;
  float s = 0.f;
  #pragma unroll
  for (int i = 0; i < 8; ++i) {
    int4 d = *(const int4*)(p + i * 512 + lane * 8);
    const u16* h = (const u16*)&d;
    #pragma unroll
    for (int j = 0; j < 8; ++j) s += b2f(h[j]);
  }
  #pragma unroll
  for (int off = 32; off; off >>= 1) s += __shfl_xor(s, off, 64);
  if (lane == 0) Ksum[row] = s;
}

// Z[t] = 1/(Q[t,:]·Ksum[batch,:] + 1e-6); one wave per token
__global__ __launch_bounds__(256)
void zden(const u16* __restrict__ Qb, const float* __restrict__ Ksum,
          float* __restrict__ Z) {
  int lane = threadIdx.x & 63;
  int t = blockIdx.x * 4 + (threadIdx.x >> 6);
  const u16* qp = Qb + (size_t)t * 1024;
  const float* ks = Ksum + (size_t)(t >> 12) * 1024;
  float s = 0.f;
  #pragma unroll
  for (int i = 0; i < 2; ++i) {
    int idx = i * 512 + lane * 8;
    int4 d = *(const int4*)(qp + idx);
    const u16* h = (const u16*)&d;
    float4 k0 = *(const float4*)(ks + idx);
    float4 k1 = *(const float4*)(ks + idx + 4);
    s += b2f(h[0]) * k0.x + b2f(h[1]) * k0.y + b2f(h[2]) * k0.z + b2f(h[3]) * k0.w
       + b2f(h[4]) * k1.x + b2f(h[5]) * k1.y + b2f(h[6]) * k1.z + b2f(h[7]) * k1.w;
  }
  #pragma unroll
  for (int off = 32; off; off >>= 1) s += __shfl_xor(s, off, 64);
  if (lane == 0) Z[t] = 1.0f / (s + 1e-6f);
}

extern "C" void kernel_launch(void* const* d_in, const int* in_sizes, int n_in,
                              void* d_out, int out_size, void* d_ws, size_t ws_size,
                              hipStream_t stream) {
  const float* q  = (const float*)d_in[0];
  const float* k  = (const float*)d_in[1];
  const float* v  = (const float*)d_in[2];
  const float* Wq = (const float*)d_in[3];
  const float* bq = (const float*)d_in[4];
  const float* Wk = (const float*)d_in[5];
  const float* bk = (const float*)d_in[6];
  const float* Wv = (const float*)d_in[7];
  const float* bv = (const float*)d_in[8];
  const float* Wo = (const float*)d_in[9];
  const float* bo = (const float*)d_in[10];
  float* out = (float*)d_out;

  // workspace layout (~112.1 MiB), aliasing chain (stream-ordered):
  u16* Wqb = (u16*)d_ws;                 // 4x 1024x1024 bf16 = 8 MiB
  u16* Wkb = Wqb + 1048576;
  u16* Wvb = Wkb + 1048576;
  u16* Wob = Wvb + 1048576;
  u16* Qb  = Wob + 1048576;              // [16384][1024] bf16, 32 MiB
  u16* KT  = Qb  + 16777216;             // [4][1024][4096] bf16, 32 MiB
  u16* VT  = KT  + 16777216;             // [4][1024][4096] bf16, 32 MiB
  u16* KVr = VT  + 16777216;             // [4][1024(d)][1024(l)] bf16, 8 MiB
  float* Ksum = (float*)(KVr + 4194304); // [4][1024] f32
  float* Z    = Ksum + 4096;             // [16384] f32
  // region reuse (each write strictly after the prior reader finishes):
  u16* Pkv = Qb;   // S2 split-K partials; dead after its reduce4 (Qproj later)
  u16* Pg  = VT;   // G split-K partials (VT dead after S2)
  u16* Gp  = KT;   // G' [4][1024(n)][1024(d)] (KT dead after S2)

  // 1. weights -> bf16 (q/k/v conversion now fused into the projections)
  wconv<<<4096, 256, 0, stream>>>(Wq, Wk, Wv, Wo, Wqb);

  // 2. K projection: KT[b][d][t] = phi(k Wk^T + bk), fp32-A fused, trans out
  dim3 gp(64, 4, 1);
  gemm_bt256<EPI_PHI_BIAS, true, true><<<gp, 512, 0, stream>>>(
      k, Wkb, bk, nullptr, KT, 16384, 1024, 1024, 1024, 1024, 0,
      0, 0, 0, 0, 0, 2);
  ksum_rows<<<1024, 256, 0, stream>>>(KT, Ksum);

  // 3. V projection (fp32-A fused)
  gemm_bt256<EPI_BIAS, true, true><<<gp, 512, 0, stream>>>(
      v, Wvb, bv, nullptr, VT, 16384, 1024, 1024, 1024, 1024, 0,
      0, 0, 0, 0, 0, 2);

  // 4. S2: KVr[d,l] = sum_t KT[d,t]*VT[l,t], split-K x4 (z = kslice*4+batch)
  dim3 g2(4, 4, 16);
  gemm_bt256<EPI_NONE, false, false><<<g2, 512, 0, stream>>>(
      KT, VT, nullptr, nullptr, Pkv, 1024, 1024, 1024, 4096, 4096, 1024,
      4194304L, 4194304L, 1048576L, 0, 3, 2);
  reduce4<<<2048, 256, 0, stream>>>(Pkv, KVr);

  // 5. G'[n,d] = sum_l Wob[n,l]*KVr[d,l], split-K x4 (K=256/slice)
  dim3 gg(4, 4, 16);
  gemm_bt256<EPI_NONE, false, false><<<gg, 512, 0, stream>>>(
      Wob, KVr, nullptr, nullptr, Pg, 1024, 1024, 256, 1024, 1024, 1024,
      0L, 1048576L, 1048576L, 0, 3, 2);
  reduce4<<<2048, 256, 0, stream>>>(Pg, Gp);

  // 6. Q projection (fp32-A fused; overwrites Pkv region after its reduce4)
  gemm_bt256<EPI_PHI_BIAS, false, true><<<gp, 512, 0, stream>>>(
      q, Wqb, bq, nullptr, Qb, 16384, 1024, 1024, 1024, 1024, 1024,
      0, 0, 0, 0, 0, 2);
  zden<<<4096, 256, 0, stream>>>(Qb, Ksum, Z);

  // 7. final: out[t,n] = Z[t]*(sum_d Qb[t,d]*G'[n,d]) + bo[n], fp32 out
  dim3 gf(16, 4, 4);
  gemm_bt256<EPI_ZBIAS_F32, false, false><<<gf, 512, 0, stream>>>(
      Qb, Gp, bo, Z, out, 4096, 1024, 1024, 1024, 1024, 1024,
      4194304L, 1048576L, 4194304L, 4096L, 3, 2);
}